// Round 13
// baseline (2553.917 us; speedup 1.0000x reference)
//
#include <hip/hip_runtime.h>
#include <hip/hip_bf16.h>
#include <stdint.h>

typedef __attribute__((ext_vector_type(4))) float f32x4;
typedef __attribute__((ext_vector_type(8))) short short8;
typedef __attribute__((ext_vector_type(4))) short short4v;

// ---------------- workspace layout (bytes) ----------------
#define OFF_XBF  ((size_t)0)            // [8192][1024] bf16 = 16777216
#define OFF_WIT  ((size_t)16777216)     // [2*4096][1024] bf16 = 16777216
#define OFF_WHT  ((size_t)33554432)     // [2*4096][1024] bf16 = 16777216
#define OFF_XG   ((size_t)50331648)     // [8192][8192] bf16 = 134217728
#define OFF_H    ((size_t)184549376)    // [2 parity][2 dir][32 prod][32 b][32 c] bf16 = 262144
#define OFF_BIAS ((size_t)184811520)    // [8192] f32 = 32768
#define OFF_LEN  ((size_t)184844288)    // [32] i32
#define OFF_CNT  ((size_t)184844416)    // flags: [2 dir][32] u32 = 256B

__device__ __forceinline__ short f2bf(float f) {
  union { float f; uint32_t u; } v; v.f = f;
  uint32_t u = v.u;
  uint32_t r = (u + 0x7fffu + ((u >> 16) & 1u)) >> 16;
  return (short)r;
}
__device__ __forceinline__ float bf2f(short s) {
  union { uint32_t u; float f; } v; v.u = ((uint32_t)(uint16_t)s) << 16;
  return v.f;
}
__device__ __forceinline__ float sigf(float z) {
  float e = __builtin_amdgcn_exp2f(z * -1.44269504f);
  return __builtin_amdgcn_rcpf(1.f + e);
}
__device__ __forceinline__ float tanhfast(float z) {
  float e = __builtin_amdgcn_exp2f(z * -2.88539008f);
  return fmaf(__builtin_amdgcn_rcpf(1.f + e), 2.f, -1.f);
}

// ---------------- lengths ----------------
__global__ void k_len(const int* __restrict__ mask, int* __restrict__ len) {
  int b = threadIdx.x;
  if (b < 32) {
    int s = 0;
    for (int t = 0; t < 256; t++) s += mask[b * 256 + t];
    len[b] = s;
  }
}

// ---------------- x -> bf16, [B,T,D] -> [(t*32+b), D] ----------------
__global__ void k_xconv(const float* __restrict__ x, short* __restrict__ xbf) {
  int bid = blockIdx.x;              // 0..8191 = b*256 + t
  int b = bid >> 8, t = bid & 255;
  int d = threadIdx.x * 4;
  const float* sp = x + ((size_t)bid) * 1024 + d;
  float4 v = *(const float4*)sp;
  short4v o;
  o.x = f2bf(v.x); o.y = f2bf(v.y); o.z = f2bf(v.z); o.w = f2bf(v.w);
  *(short4v*)(xbf + ((size_t)(t * 32 + b)) * 1024 + d) = o;
}

// ------- weights: transpose [k][4096] f32 -> [n_perm][k] bf16, gate-interleaved perm -------
// perm: p = g4*16 + gate*4 + h4  <->  orig col c = gate*1024 + g4*4 + h4
__global__ void k_wprep(const float* __restrict__ Wi_f, const float* __restrict__ Wi_b,
                        const float* __restrict__ Wh_f, const float* __restrict__ Wh_b,
                        short* __restrict__ WiT, short* __restrict__ WhT) {
  __shared__ short ldsT[64 * 72];
  int id = blockIdx.x;               // 4096 blocks
  int which = id >> 11, dir = (id >> 10) & 1, tile = id & 1023;
  int kt = (tile >> 6) * 64, c0 = (tile & 63) * 64;
  const float* src = (which == 0) ? (dir == 0 ? Wi_f : Wi_b)
                                  : (dir == 0 ? Wh_f : Wh_b);
  short* dst = (which == 0) ? WiT : WhT;
  int tid = threadIdx.x;
#pragma unroll 4
  for (int i = 0; i < 16; i++) {
    int idx = i * 256 + tid;
    int kk = idx >> 6, cc = idx & 63;
    float v = src[(size_t)(kt + kk) * 4096 + c0 + cc];
    ldsT[cc * 72 + kk] = f2bf(v);    // transposed store
  }
  __syncthreads();
  int rowc = tid >> 2, part = tid & 3;
  int cg = c0 + rowc;
  int gate = cg >> 10, hc = cg & 1023;
  int p = (hc >> 2) * 16 + gate * 4 + (hc & 3);
  int n = dir * 4096 + p;
  short8 v0 = *(short8*)&ldsT[rowc * 72 + part * 16];
  short8 v1 = *(short8*)&ldsT[rowc * 72 + part * 16 + 8];
  *(short8*)(dst + (size_t)n * 1024 + kt + part * 16) = v0;
  *(short8*)(dst + (size_t)n * 1024 + kt + part * 16 + 8) = v1;
}

// ---------------- bias permute ----------------
__global__ void k_bias(const float* __restrict__ bf_, const float* __restrict__ bb_,
                       float* __restrict__ bp) {
  int n = blockIdx.x * 256 + threadIdx.x;   // 0..8191
  int dir = n >> 12, p = n & 4095;
  int gate = (p >> 2) & 3, g4 = p >> 4, h4 = p & 3;
  int c = gate * 1024 + g4 * 4 + h4;
  bp[n] = (dir == 0 ? bf_ : bb_)[c];
}

// ---------------- XG = xbf @ WiT^T + bias : [8192][8192] bf16 ----------------
__global__ void k_gemm(const short* __restrict__ Abf,
                       const short* __restrict__ Bbf,
                       const float* __restrict__ bias,
                       short* __restrict__ C) {
  __shared__ char Ash[128 * 144];
  __shared__ char Bsh[128 * 144];
  const int tid = threadIdx.x;
  const int lane = tid & 63, wid = tid >> 6;
  const int wm = wid >> 1, wn = wid & 1;
  const int l15 = lane & 15, lg = lane >> 4;
  const int m0 = blockIdx.y * 128, n0 = blockIdx.x * 128;

  f32x4 acc[4][4];
#pragma unroll
  for (int i = 0; i < 4; i++)
#pragma unroll
    for (int j = 0; j < 4; j++) acc[i][j] = (f32x4){0.f, 0.f, 0.f, 0.f};

  for (int kt = 0; kt < 1024; kt += 64) {
#pragma unroll
    for (int i = 0; i < 4; i++) {
      int chunk = i * 256 + tid;
      int row = chunk >> 3, kc = chunk & 7;
      *(short8*)(Ash + row * 144 + kc * 16) =
          *(const short8*)(Abf + (size_t)(m0 + row) * 1024 + kt + kc * 8);
      *(short8*)(Bsh + row * 144 + kc * 16) =
          *(const short8*)(Bbf + (size_t)(n0 + row) * 1024 + kt + kc * 8);
    }
    __syncthreads();
#pragma unroll
    for (int kk = 0; kk < 2; kk++) {
      short8 af[4], bfv[4];
#pragma unroll
      for (int mt = 0; mt < 4; mt++)
        af[mt] = *(const short8*)(Ash + (wm * 64 + mt * 16 + l15) * 144 + kk * 64 + lg * 16);
#pragma unroll
      for (int ntc = 0; ntc < 4; ntc++)
        bfv[ntc] = *(const short8*)(Bsh + (wn * 64 + ntc * 16 + l15) * 144 + kk * 64 + lg * 16);
#pragma unroll
      for (int mt = 0; mt < 4; mt++)
#pragma unroll
        for (int ntc = 0; ntc < 4; ntc++)
          acc[mt][ntc] = __builtin_amdgcn_mfma_f32_16x16x32_bf16(af[mt], bfv[ntc], acc[mt][ntc], 0, 0, 0);
    }
    __syncthreads();
  }
  float bs[4];
#pragma unroll
  for (int ntc = 0; ntc < 4; ntc++) bs[ntc] = bias[n0 + wn * 64 + ntc * 16 + l15];
#pragma unroll
  for (int mt = 0; mt < 4; mt++) {
    int row = m0 + wm * 64 + mt * 16 + lg * 4;
#pragma unroll
    for (int ntc = 0; ntc < 4; ntc++) {
      int col = n0 + wn * 64 + ntc * 16 + l15;
#pragma unroll
      for (int r = 0; r < 4; r++)
        C[(size_t)(row + r) * 8192 + col] = f2bf(acc[mt][ntc][r] + bs[ntc]);
    }
  }
}

// ---------------- persistent recurrence (R10 protocol, 32 producers/dir) ----------------
// 64 blocks x 512 thr (8 waves). dir = bid>>5, nblk = bid&31 owns permuted
// z-cols [nblk*128,+128) = h-cols [nblk*32,+32), ALL 32 batches.
// Wave nt: 16 z-cols x 32 batches (2 batch-groups, 64 MFMA). Wh in 128 VGPR/wave.
// h layout: [parity][dir][producer][32 batch][32 col] bf16 (2KB/producer).
// Publish: gates -> 2KB LDS Pub; wave0 stores it (2x dwordx4 sc0 sc1/lane, 16 lines),
// drains, flags. Consume: wave w polls its 4 producers' flags, stages 4x2KB
// (MALL-direct sc0 sc1) as soon as they land. Skew tail = max over 32, not 64.
__global__ void __launch_bounds__(512, 1) k_recur(
    const short* __restrict__ XG,    // [8192][8192] bf16
    const short* __restrict__ WhT,   // [2*4096][1024] bf16
    const int* __restrict__ len,
    short* __restrict__ hbuf,        // [2][2][32][32][32] bf16
    float* __restrict__ out,         // [32][256][2048] f32
    unsigned int* __restrict__ flags) {  // [2][32]
  __shared__ char Hld[67584];        // 64KB staged h + 2KB publish buffer
  char* Pub = Hld + 65536;
  char* hb = (char*)hbuf;
  const int tid = threadIdx.x;
  const int lane = tid & 63;
  const int wid = tid >> 6;          // nt 0..7
  const int bidx = blockIdx.x;
  const int dir = bidx >> 5;
  const int nblk = bidx & 31;
  const int nt = wid;
  const int l15 = lane & 15, lg = lane >> 4;

  // B-fragments (Wh columns), resident in registers for all 256 steps
  const int ncol = dir * 4096 + nblk * 128 + nt * 16 + l15;
  const short* wrow = WhT + (size_t)ncol * 1024;
  short8 bfr[32];
#pragma unroll
  for (int kk = 0; kk < 32; kk++)
    bfr[kk] = *(const short8*)(wrow + kk * 32 + lg * 8);

  float c_reg[2][4] = {{0.f,0.f,0.f,0.f},{0.f,0.f,0.f,0.f}};
  int lenv[2][4];
  float xg_pf[2][4];
#pragma unroll
  for (int mt = 0; mt < 2; mt++)
#pragma unroll
    for (int r = 0; r < 4; r++) {
      int b_r = mt * 16 + lg * 4 + r;
      lenv[mt][r] = len[b_r];
      int tt = (dir == 0) ? 0 : ((lenv[mt][r] - 1) & 255);
      xg_pf[mt][r] = bf2f(XG[(size_t)(tt * 32 + b_r) * 8192 + ncol]);
    }

  const int c4 = l15;
  const int gate = c4 >> 2;
  const int sw = (l15 & 7) << 4;     // batch-row swizzle (mt*16 preserves &7 via <<4 granule)
  const int hcol0 = nblk * 32 + nt * 4;
  unsigned int* dflags = flags + dir * 32;

  // stage constants: wave wid stages producers [wid*4, wid*4+4); lane covers
  // batch row (lane&31), 32B half (lane>>5) of the producer's 64B row segment
  const int srow = lane & 31;
  const int shalf = lane >> 5;
  const int mysw = (srow & 7) << 4;

  for (int t = 0; t < 256; t++) {
    const char* tb = hb + (size_t)((t & 1) * 2 + dir) * 65536;
    char* tbn      = hb + (size_t)(((t + 1) & 1) * 2 + dir) * 65536;

    // ---- W∥S: poll own 4 producers' flags, then stage their 4x2KB ----
    {
      const unsigned int* fl = dflags + wid * 4 + (lane & 3);
      unsigned int tgt = (unsigned int)t;
      for (;;) {
        unsigned int v = __hip_atomic_load(fl, __ATOMIC_RELAXED, __HIP_MEMORY_SCOPE_AGENT);
        if (__all((int)(v >= tgt))) break;
      }
      __builtin_amdgcn_sched_barrier(0);
      f32x4 sv[4][2];
#pragma unroll
      for (int p = 0; p < 4; p++) {
        const char* a = tb + (wid * 4 + p) * 2048 + srow * 64 + shalf * 32;
        asm volatile("global_load_dwordx4 %0, %1, off sc0 sc1" : "=v"(sv[p][0]) : "v"(a));
        asm volatile("global_load_dwordx4 %0, %1, off sc0 sc1" : "=v"(sv[p][1]) : "v"(a + 16));
      }
      asm volatile("s_waitcnt vmcnt(0)" ::: "memory");
      __builtin_amdgcn_sched_barrier(0);
#pragma unroll
      for (int p = 0; p < 4; p++) {
        int off = srow * 2048 + (wid * 4 + p) * 64 + shalf * 32;
        *(f32x4*)(Hld + (off ^ mysw)) = sv[p][0];
        *(f32x4*)(Hld + ((off + 16) ^ mysw)) = sv[p][1];
      }
    }
    __syncthreads();

    // ---- MFMA: 2 batch-groups x 2 independent chains ----
    f32x4 acc[2][2];
#pragma unroll
    for (int mt = 0; mt < 2; mt++) {
      acc[mt][0] = (f32x4){0.f, 0.f, 0.f, 0.f};
      acc[mt][1] = (f32x4){0.f, 0.f, 0.f, 0.f};
      const int ab = (mt * 16 + l15) * 2048 + (lg << 4);
#pragma unroll
      for (int kk = 0; kk < 16; kk++) {
        short8 afA = *(const short8*)(Hld + ((ab + kk * 64) ^ sw));
        short8 afB = *(const short8*)(Hld + ((ab + (kk + 16) * 64) ^ sw));
        acc[mt][0] = __builtin_amdgcn_mfma_f32_16x16x32_bf16(afA, bfr[kk], acc[mt][0], 0, 0, 0);
        acc[mt][1] = __builtin_amdgcn_mfma_f32_16x16x32_bf16(afB, bfr[kk + 16], acc[mt][1], 0, 0, 0);
      }
    }

    // ---- gates (fast exp2 math); h -> Pub (LDS), packed saves for out ----
    uint32_t hsv0[2][4], hsv1[2][4];
#pragma unroll
    for (int mt = 0; mt < 2; mt++)
#pragma unroll
      for (int r = 0; r < 4; r++) {
        int b_r = mt * 16 + lg * 4 + r;
        float z = acc[mt][0][r] + acc[mt][1][r] + xg_pf[mt][r];
        float s = (gate == 2) ? tanhfast(z) : sigf(z);
        float x8 = __shfl_xor(s, 8);     // i<->g, f<->o
        float pI = s * x8;               // on i-lanes: sig(i)*tanh(g)
        float v = (gate == 0) ? pI : s;
        float x4 = __shfl_xor(v, 4);     // i-lane receives sig(f)
        float o4 = __shfl_xor(x8, 4);    // i-lane receives sig(o)
        float cn = fmaf(x4, c_reg[mt][r], pI);
        float h = o4 * tanhfast(cn);
        if (c4 < 4) c_reg[mt][r] = cn;
        uint32_t hb16 = (uint32_t)(uint16_t)f2bf(h);
        uint32_t p0 = hb16 | (__shfl_xor(hb16, 1) << 16);
        uint32_t q  = __shfl_xor(p0, 2);
        hsv0[mt][r] = p0; hsv1[mt][r] = q;
        if (c4 == 0) {
          unsigned long long p = (unsigned long long)p0 | ((unsigned long long)q << 32);
          *(unsigned long long*)(Pub + b_r * 64 + nt * 8) = p;
        }
      }
    __syncthreads();   // Pub complete; Hld MFMA reads complete

    // ---- publish: wave0 stores the block's 2KB region, drains, flags ----
    if (wid == 0) {
      f32x4 pv0 = *(const f32x4*)(Pub + lane * 32);
      f32x4 pv1 = *(const f32x4*)(Pub + lane * 32 + 16);
      char* d = tbn + nblk * 2048 + lane * 32;
      asm volatile("global_store_dwordx4 %0, %1, off sc0 sc1" :: "v"(d), "v"(pv0) : "memory");
      asm volatile("global_store_dwordx4 %0, %1, off sc0 sc1" :: "v"(d + 16), "v"(pv1) : "memory");
      asm volatile("s_waitcnt vmcnt(0)" ::: "memory");
      if (lane == 0)
        __hip_atomic_store(dflags + nblk, (unsigned int)(t + 1),
                           __ATOMIC_RELAXED, __HIP_MEMORY_SCOPE_AGENT);
    }
    __builtin_amdgcn_sched_barrier(0);

    // ---- D (straggler shadow): out stores + XG prefetch t+1 ----
    if (c4 == 0) {
#pragma unroll
      for (int mt = 0; mt < 2; mt++)
#pragma unroll
        for (int r = 0; r < 4; r++) {
          int b_r = mt * 16 + lg * 4 + r;
          int tt = (dir == 0) ? t : ((lenv[mt][r] - 1 - t) & 255);
          f32x4 hv;
          hv.x = bf2f((short)(hsv0[mt][r] & 0xffff));
          hv.y = bf2f((short)(hsv0[mt][r] >> 16));
          hv.z = bf2f((short)(hsv1[mt][r] & 0xffff));
          hv.w = bf2f((short)(hsv1[mt][r] >> 16));
          *(f32x4*)(out + ((size_t)b_r * 256 + tt) * 2048 + dir * 1024 + hcol0) = hv;
        }
    }
    int tn = (t < 255) ? t + 1 : 255;
#pragma unroll
    for (int mt = 0; mt < 2; mt++)
#pragma unroll
      for (int r = 0; r < 4; r++) {
        int b_r = mt * 16 + lg * 4 + r;
        int tt = (dir == 0) ? tn : ((lenv[mt][r] - 1 - tn) & 255);
        xg_pf[mt][r] = bf2f(XG[(size_t)(tt * 32 + b_r) * 8192 + ncol]);
      }
  }
}

extern "C" void kernel_launch(void* const* d_in, const int* in_sizes, int n_in,
                              void* d_out, int out_size, void* d_ws, size_t ws_size,
                              hipStream_t stream) {
  const float* x    = (const float*)d_in[0];
  const int*   mask = (const int*)d_in[1];
  const float* Wi_f = (const float*)d_in[2];
  const float* Wh_f = (const float*)d_in[3];
  const float* b_f  = (const float*)d_in[4];
  const float* Wi_b = (const float*)d_in[5];
  const float* Wh_b = (const float*)d_in[6];
  const float* b_b  = (const float*)d_in[7];
  float* out = (float*)d_out;
  char* ws = (char*)d_ws;

  short* xbf  = (short*)(ws + OFF_XBF);
  short* WiT  = (short*)(ws + OFF_WIT);
  short* WhT  = (short*)(ws + OFF_WHT);
  short* XG   = (short*)(ws + OFF_XG);
  short* hbuf = (short*)(ws + OFF_H);
  float* bp   = (float*)(ws + OFF_BIAS);
  int*   len  = (int*)(ws + OFF_LEN);
  unsigned int* flags = (unsigned int*)(ws + OFF_CNT);

  hipMemsetAsync(hbuf, 0, 262144, stream);
  hipMemsetAsync(flags, 0, 512, stream);

  k_len<<<1, 64, 0, stream>>>(mask, len);
  k_xconv<<<8192, 256, 0, stream>>>(x, xbf);
  k_wprep<<<4096, 256, 0, stream>>>(Wi_f, Wi_b, Wh_f, Wh_b, WiT, WhT);
  k_bias<<<32, 256, 0, stream>>>(b_f, b_b, bp);

  dim3 g(64, 64);
  k_gemm<<<g, 256, 0, stream>>>(xbf, WiT, bp, XG);

  k_recur<<<64, 512, 0, stream>>>(XG, WhT, len, hbuf, out, flags);
}

// Round 14
// 1359.036 us; speedup vs baseline: 1.8792x; 1.8792x over previous
//
#include <hip/hip_runtime.h>
#include <hip/hip_bf16.h>
#include <stdint.h>

typedef __attribute__((ext_vector_type(4))) float f32x4;
typedef __attribute__((ext_vector_type(8))) short short8;
typedef __attribute__((ext_vector_type(4))) short short4v;

// ---------------- workspace layout (bytes) ----------------
#define OFF_XBF  ((size_t)0)            // [8192][1024] bf16 = 16777216
#define OFF_WIT  ((size_t)16777216)     // [2*4096][1024] bf16 = 16777216
#define OFF_WHT  ((size_t)33554432)     // [2*4096][1024] bf16 = 16777216
#define OFF_XG   ((size_t)50331648)     // [8192][8192] bf16 = 134217728
#define OFF_H    ((size_t)184549376)    // [2 parity][2 dir][64 prod][32][16] bf16 = 262144
#define OFF_BIAS ((size_t)184811520)    // [8192] f32 = 32768
#define OFF_LEN  ((size_t)184844288)    // [32] i32
#define OFF_CNT  ((size_t)184844416)    // flags: [2 dir][64] u32 = 512B

__device__ __forceinline__ short f2bf(float f) {
  union { float f; uint32_t u; } v; v.f = f;
  uint32_t u = v.u;
  uint32_t r = (u + 0x7fffu + ((u >> 16) & 1u)) >> 16;
  return (short)r;
}
__device__ __forceinline__ float bf2f(short s) {
  union { uint32_t u; float f; } v; v.u = ((uint32_t)(uint16_t)s) << 16;
  return v.f;
}
__device__ __forceinline__ float sigf(float z) {
  float e = __builtin_amdgcn_exp2f(z * -1.44269504f);
  return __builtin_amdgcn_rcpf(1.f + e);
}
__device__ __forceinline__ float tanhfast(float z) {
  float e = __builtin_amdgcn_exp2f(z * -2.88539008f);
  return fmaf(__builtin_amdgcn_rcpf(1.f + e), 2.f, -1.f);
}

// ---------------- lengths ----------------
__global__ void k_len(const int* __restrict__ mask, int* __restrict__ len) {
  int b = threadIdx.x;
  if (b < 32) {
    int s = 0;
    for (int t = 0; t < 256; t++) s += mask[b * 256 + t];
    len[b] = s;
  }
}

// ---------------- x -> bf16, [B,T,D] -> [(t*32+b), D] ----------------
__global__ void k_xconv(const float* __restrict__ x, short* __restrict__ xbf) {
  int bid = blockIdx.x;              // 0..8191 = b*256 + t
  int b = bid >> 8, t = bid & 255;
  int d = threadIdx.x * 4;
  const float* sp = x + ((size_t)bid) * 1024 + d;
  float4 v = *(const float4*)sp;
  short4v o;
  o.x = f2bf(v.x); o.y = f2bf(v.y); o.z = f2bf(v.z); o.w = f2bf(v.w);
  *(short4v*)(xbf + ((size_t)(t * 32 + b)) * 1024 + d) = o;
}

// ------- weights: transpose [k][4096] f32 -> [n_perm][k] bf16, gate-interleaved perm -------
// perm: p = g4*16 + gate*4 + h4  <->  orig col c = gate*1024 + g4*4 + h4
__global__ void k_wprep(const float* __restrict__ Wi_f, const float* __restrict__ Wi_b,
                        const float* __restrict__ Wh_f, const float* __restrict__ Wh_b,
                        short* __restrict__ WiT, short* __restrict__ WhT) {
  __shared__ short ldsT[64 * 72];
  int id = blockIdx.x;               // 4096 blocks
  int which = id >> 11, dir = (id >> 10) & 1, tile = id & 1023;
  int kt = (tile >> 6) * 64, c0 = (tile & 63) * 64;
  const float* src = (which == 0) ? (dir == 0 ? Wi_f : Wi_b)
                                  : (dir == 0 ? Wh_f : Wh_b);
  short* dst = (which == 0) ? WiT : WhT;
  int tid = threadIdx.x;
#pragma unroll 4
  for (int i = 0; i < 16; i++) {
    int idx = i * 256 + tid;
    int kk = idx >> 6, cc = idx & 63;
    float v = src[(size_t)(kt + kk) * 4096 + c0 + cc];
    ldsT[cc * 72 + kk] = f2bf(v);    // transposed store
  }
  __syncthreads();
  int rowc = tid >> 2, part = tid & 3;
  int cg = c0 + rowc;
  int gate = cg >> 10, hc = cg & 1023;
  int p = (hc >> 2) * 16 + gate * 4 + (hc & 3);
  int n = dir * 4096 + p;
  short8 v0 = *(short8*)&ldsT[rowc * 72 + part * 16];
  short8 v1 = *(short8*)&ldsT[rowc * 72 + part * 16 + 8];
  *(short8*)(dst + (size_t)n * 1024 + kt + part * 16) = v0;
  *(short8*)(dst + (size_t)n * 1024 + kt + part * 16 + 8) = v1;
}

// ---------------- bias permute ----------------
__global__ void k_bias(const float* __restrict__ bf_, const float* __restrict__ bb_,
                       float* __restrict__ bp) {
  int n = blockIdx.x * 256 + threadIdx.x;   // 0..8191
  int dir = n >> 12, p = n & 4095;
  int gate = (p >> 2) & 3, g4 = p >> 4, h4 = p & 3;
  int c = gate * 1024 + g4 * 4 + h4;
  bp[n] = (dir == 0 ? bf_ : bb_)[c];
}

// ---------------- XG = xbf @ WiT^T + bias : [8192][8192] bf16 ----------------
// m97-style: global_load_lds width=16 into LINEAR LDS [128][64] (no pad), no VGPR
// round-trip. Lane l's 16B lands at chunk_base + l*16 = (l>>3)*128 + (l&7)*16,
// matching [row][128B] layout exactly (wave-uniform LDS base, per-lane global src).
__global__ void k_gemm(const short* __restrict__ Abf,
                       const short* __restrict__ Bbf,
                       const float* __restrict__ bias,
                       short* __restrict__ C) {
  __shared__ short Ash[128 * 64];
  __shared__ short Bsh[128 * 64];
  const int tid = threadIdx.x;
  const int lane = tid & 63, wid = tid >> 6;   // 4 waves
  const int wm = wid >> 1, wn = wid & 1;
  const int l15 = lane & 15, lg = lane >> 4;
  const int m0 = blockIdx.y * 128, n0 = blockIdx.x * 128;
  const int srow = wid * 32;                   // wave's staging row base
  const int lrow = lane >> 3, lkc = lane & 7;  // row-in-chunk, 16B column

  f32x4 acc[4][4];
#pragma unroll
  for (int i = 0; i < 4; i++)
#pragma unroll
    for (int j = 0; j < 4; j++) acc[i][j] = (f32x4){0.f, 0.f, 0.f, 0.f};

  for (int kt = 0; kt < 1024; kt += 64) {
#pragma unroll
    for (int i = 0; i < 4; i++) {
      int row = srow + i * 8 + lrow;
      __builtin_amdgcn_global_load_lds(
          (const __attribute__((address_space(1))) void*)
              (Abf + (size_t)(m0 + row) * 1024 + kt + lkc * 8),
          (__attribute__((address_space(3))) void*)(Ash + (srow + i * 8) * 64),
          16, 0, 0);
      __builtin_amdgcn_global_load_lds(
          (const __attribute__((address_space(1))) void*)
              (Bbf + (size_t)(n0 + row) * 1024 + kt + lkc * 8),
          (__attribute__((address_space(3))) void*)(Bsh + (srow + i * 8) * 64),
          16, 0, 0);
    }
    __syncthreads();
#pragma unroll
    for (int kk = 0; kk < 2; kk++) {
      short8 af[4], bfv[4];
#pragma unroll
      for (int mt = 0; mt < 4; mt++)
        af[mt] = *(const short8*)(Ash + (wm * 64 + mt * 16 + l15) * 64 + kk * 32 + lg * 8);
#pragma unroll
      for (int ntc = 0; ntc < 4; ntc++)
        bfv[ntc] = *(const short8*)(Bsh + (wn * 64 + ntc * 16 + l15) * 64 + kk * 32 + lg * 8);
#pragma unroll
      for (int mt = 0; mt < 4; mt++)
#pragma unroll
        for (int ntc = 0; ntc < 4; ntc++)
          acc[mt][ntc] = __builtin_amdgcn_mfma_f32_16x16x32_bf16(af[mt], bfv[ntc], acc[mt][ntc], 0, 0, 0);
    }
    __syncthreads();
  }
  float bs[4];
#pragma unroll
  for (int ntc = 0; ntc < 4; ntc++) bs[ntc] = bias[n0 + wn * 64 + ntc * 16 + l15];
#pragma unroll
  for (int mt = 0; mt < 4; mt++) {
    int row = m0 + wm * 64 + mt * 16 + lg * 4;
#pragma unroll
    for (int ntc = 0; ntc < 4; ntc++) {
      int col = n0 + wn * 64 + ntc * 16 + l15;
#pragma unroll
      for (int r = 0; r < 4; r++)
        C[(size_t)(row + r) * 8192 + col] = f2bf(acc[mt][ntc][r] + bs[ntc]);
    }
  }
}

// ---------------- persistent recurrence (R10: pipelined detect+stage) ----------------
// 128 blocks x 512 thr (8 waves). dir = bid>>6, nblk = bid&63 owns permuted
// z-cols [nblk*64,+64) = h-cols [nblk*16,+16). Wave (mt,nt): 16 batches x 16 cols.
// h layout: [parity][dir][producer nblk][32 batch][16 col] bf16 (1KB/producer).
// Publish: gates write h into 1KB LDS buffer; wave0 stores the whole region with
// ONE global_store_dwordx4 sc0 sc1 (write-through to MALL, 8 full lines), drains,
// flags. Consume: wave w polls only producers [8w,8w+8), stages their 8KB as soon
// as those flags land (MALL-direct sc0 sc1 loads) -> detect/stage pipelined.
__global__ void __launch_bounds__(512, 1) k_recur(
    const short* __restrict__ XG,    // [8192][8192] bf16
    const short* __restrict__ WhT,   // [2*4096][1024] bf16
    const int* __restrict__ len,
    short* __restrict__ hbuf,        // [2][2][64][32][16] bf16
    float* __restrict__ out,         // [32][256][2048] f32
    unsigned int* __restrict__ flags) {  // [2][64]
  __shared__ char Hld[66560];        // 64KB staged h + 1KB publish buffer
  char* Pub = Hld + 65536;
  char* hb = (char*)hbuf;
  const int tid = threadIdx.x;
  const int lane = tid & 63;
  const int wid = tid >> 6;
  const int bidx = blockIdx.x;
  const int dir = bidx >> 6;
  const int nblk = bidx & 63;
  const int mt = wid >> 2, nt = wid & 3;
  const int l15 = lane & 15, lg = lane >> 4;

  // B-fragments (Wh columns), resident in registers for all 256 steps
  const int ncol = dir * 4096 + nblk * 64 + nt * 16 + l15;
  const short* wrow = WhT + (size_t)ncol * 1024;
  short8 bfr[32];
#pragma unroll
  for (int kk = 0; kk < 32; kk++)
    bfr[kk] = *(const short8*)(wrow + kk * 32 + lg * 8);

  float c_reg[4] = {0.f, 0.f, 0.f, 0.f};
  int lenv[4];
#pragma unroll
  for (int r = 0; r < 4; r++) lenv[r] = len[mt * 16 + lg * 4 + r];

  const int c4 = l15;
  const int gate = c4 >> 2;
  const int brow = mt * 16 + l15;
  const int sw = (brow & 7) << 4;
  const int abase = brow * 2048 + (lg << 4);
  const int hcol0 = nblk * 16 + nt * 4;
  unsigned int* dflags = flags + dir * 64;

  // prefetch XG for t=0
  float xg_pf[4];
#pragma unroll
  for (int r = 0; r < 4; r++) {
    int b_r = mt * 16 + lg * 4 + r;
    int tt = (dir == 0) ? 0 : ((lenv[r] - 1) & 255);
    xg_pf[r] = bf2f(XG[(size_t)(tt * 32 + b_r) * 8192 + ncol]);
  }

  // per-wave stage constants: wave wid stages producers [wid*8, wid*8+8)
  const int myb = lane >> 1;                  // batch row this lane writes
  const int mysw = (myb & 7) << 4;
  const int mybase = myb * 2048 + (lane & 1) * 16;

  for (int t = 0; t < 256; t++) {
    // ---- W∥S: wave-local poll of 8 producers, then stage their 8KB ----
    {
      const unsigned int* fl = dflags + wid * 8 + (lane & 7);
      unsigned int tgt = (unsigned int)t;
      for (;;) {
        unsigned int v = __hip_atomic_load(fl, __ATOMIC_RELAXED, __HIP_MEMORY_SCOPE_AGENT);
        if (__all((int)(v >= tgt))) break;
      }
      __builtin_amdgcn_sched_barrier(0);
      const char* hsrcB = hb + (size_t)(((t & 1) * 2 + dir) * 65536);
      f32x4 sv[8];
#pragma unroll
      for (int j = 0; j < 8; j++) {
        const char* a = hsrcB + (wid * 8 + j) * 1024 + lane * 16;
        asm volatile("global_load_dwordx4 %0, %1, off sc0 sc1" : "=v"(sv[j]) : "v"(a));
      }
      asm volatile("s_waitcnt vmcnt(0)" ::: "memory");
      __builtin_amdgcn_sched_barrier(0);
#pragma unroll
      for (int j = 0; j < 8; j++) {
        // region p = wid*8+j covers cols [p*16,+16); lane writes 16B = 8 cols
        int off = (mybase + (wid * 8 + j) * 32) ^ mysw;
        *(f32x4*)(Hld + off) = sv[j];
      }
    }
    __syncthreads();

    // ---- two independent MFMA chains ----
    f32x4 accA = (f32x4){0.f, 0.f, 0.f, 0.f};
    f32x4 accB = (f32x4){0.f, 0.f, 0.f, 0.f};
#pragma unroll
    for (int kk = 0; kk < 16; kk++) {
      short8 afA = *(const short8*)(Hld + ((abase + kk * 64) ^ sw));
      short8 afB = *(const short8*)(Hld + ((abase + (kk + 16) * 64) ^ sw));
      accA = __builtin_amdgcn_mfma_f32_16x16x32_bf16(afA, bfr[kk], accA, 0, 0, 0);
      accB = __builtin_amdgcn_mfma_f32_16x16x32_bf16(afB, bfr[kk + 16], accB, 0, 0, 0);
    }

    // ---- gates (fast exp2 math); h -> Pub (LDS) ----
    f32x4 hsave[4];
#pragma unroll
    for (int r = 0; r < 4; r++) {
      int b_r = mt * 16 + lg * 4 + r;
      float z = accA[r] + accB[r] + xg_pf[r];
      float s = (gate == 2) ? tanhfast(z) : sigf(z);
      float x8 = __shfl_xor(s, 8);     // i<->g, f<->o
      float pI = s * x8;               // on i-lanes: sig(i)*tanh(g)
      float v = (gate == 0) ? pI : s;
      float x4 = __shfl_xor(v, 4);     // i-lane receives sig(f)
      float o4 = __shfl_xor(x8, 4);    // i-lane receives sig(o)
      float cn = fmaf(x4, c_reg[r], pI);
      float h = o4 * tanhfast(cn);
      if (c4 < 4) c_reg[r] = cn;
      uint32_t hb16 = (uint32_t)(uint16_t)f2bf(h);
      uint32_t p0 = hb16 | (__shfl_xor(hb16, 1) << 16);
      uint32_t q  = __shfl_xor(p0, 2);
      if (c4 == 0) {
        unsigned long long p = (unsigned long long)p0 | ((unsigned long long)q << 32);
        *(unsigned long long*)(Pub + b_r * 32 + nt * 8) = p;
        hsave[r].x = bf2f((short)(p0 & 0xffff));
        hsave[r].y = bf2f((short)(p0 >> 16));
        hsave[r].z = bf2f((short)(q & 0xffff));
        hsave[r].w = bf2f((short)(q >> 16));
      }
    }
    __syncthreads();   // Pub complete; Hld MFMA reads complete

    // ---- publish: wave0 stores the block's 1KB region, drains, flags ----
    if (wid == 0) {
      f32x4 pv = *(const f32x4*)(Pub + lane * 16);
      char* hdstB = hb + (size_t)((((t + 1) & 1) * 2 + dir) * 65536) + nblk * 1024 + lane * 16;
      asm volatile("global_store_dwordx4 %0, %1, off sc0 sc1" :: "v"(hdstB), "v"(pv) : "memory");
      asm volatile("s_waitcnt vmcnt(0)" ::: "memory");
      if (lane == 0)
        __hip_atomic_store(dflags + nblk, (unsigned int)(t + 1),
                           __ATOMIC_RELAXED, __HIP_MEMORY_SCOPE_AGENT);
    }
    __builtin_amdgcn_sched_barrier(0);

    // ---- D (straggler shadow): out stores + XG prefetch t+1 ----
    if (c4 == 0) {
#pragma unroll
      for (int r = 0; r < 4; r++) {
        int b_r = mt * 16 + lg * 4 + r;
        int tt = (dir == 0) ? t : ((lenv[r] - 1 - t) & 255);
        *(f32x4*)(out + ((size_t)b_r * 256 + tt) * 2048 + dir * 1024 + hcol0) = hsave[r];
      }
    }
    int tn = (t < 255) ? t + 1 : 255;
#pragma unroll
    for (int r = 0; r < 4; r++) {
      int b_r = mt * 16 + lg * 4 + r;
      int tt = (dir == 0) ? tn : ((lenv[r] - 1 - tn) & 255);
      xg_pf[r] = bf2f(XG[(size_t)(tt * 32 + b_r) * 8192 + ncol]);
    }
  }
}

extern "C" void kernel_launch(void* const* d_in, const int* in_sizes, int n_in,
                              void* d_out, int out_size, void* d_ws, size_t ws_size,
                              hipStream_t stream) {
  const float* x    = (const float*)d_in[0];
  const int*   mask = (const int*)d_in[1];
  const float* Wi_f = (const float*)d_in[2];
  const float* Wh_f = (const float*)d_in[3];
  const float* b_f  = (const float*)d_in[4];
  const float* Wi_b = (const float*)d_in[5];
  const float* Wh_b = (const float*)d_in[6];
  const float* b_b  = (const float*)d_in[7];
  float* out = (float*)d_out;
  char* ws = (char*)d_ws;

  short* xbf  = (short*)(ws + OFF_XBF);
  short* WiT  = (short*)(ws + OFF_WIT);
  short* WhT  = (short*)(ws + OFF_WHT);
  short* XG   = (short*)(ws + OFF_XG);
  short* hbuf = (short*)(ws + OFF_H);
  float* bp   = (float*)(ws + OFF_BIAS);
  int*   len  = (int*)(ws + OFF_LEN);
  unsigned int* flags = (unsigned int*)(ws + OFF_CNT);

  hipMemsetAsync(hbuf, 0, 262144, stream);
  hipMemsetAsync(flags, 0, 512, stream);

  k_len<<<1, 64, 0, stream>>>(mask, len);
  k_xconv<<<8192, 256, 0, stream>>>(x, xbf);
  k_wprep<<<4096, 256, 0, stream>>>(Wi_f, Wi_b, Wh_f, Wh_b, WiT, WhT);
  k_bias<<<32, 256, 0, stream>>>(b_f, b_b, bp);

  dim3 g(64, 64);
  k_gemm<<<g, 256, 0, stream>>>(xbf, WiT, bp, XG);

  k_recur<<<128, 512, 0, stream>>>(XG, WhT, len, hbuf, out, flags);
}